// Round 9
// baseline (198.724 us; speedup 1.0000x reference)
//
#include <hip/hip_runtime.h>
#include <stdint.h>

typedef __bf16 bf16;
typedef bf16 bf16x8 __attribute__((ext_vector_type(8)));
typedef _Float16 f16;
typedef f16 f16x8 __attribute__((ext_vector_type(8)));
typedef f16 f16x4 __attribute__((ext_vector_type(4)));
typedef float f32x4 __attribute__((ext_vector_type(4)));
typedef float f32x16 __attribute__((ext_vector_type(16)));
typedef unsigned short u16;
typedef unsigned int u32;
typedef u32 u32x2 __attribute__((ext_vector_type(2)));
typedef u16 u16x8v __attribute__((ext_vector_type(8)));

#define LOG2E 1.44269504088896340736f

__device__ __forceinline__ u16 f2bf(float f) {
  u32 u = __float_as_uint(f);
  u32 r = u + 0x7fffu + ((u >> 16) & 1u);
  return (u16)(r >> 16);
}
__device__ __forceinline__ float bf2f(u16 h) { return __uint_as_float(((u32)h) << 16); }

__device__ __forceinline__ u32 pkrtz(float a, float b) {
  auto r = __builtin_amdgcn_cvt_pkrtz(a, b);   // f16x2: a->[15:0], b->[31:16]
  u32 u; __builtin_memcpy(&u, &r, 4);
  return u;
}
// cross-32 reduce helpers via permlane32_swap (VALU, no LDS pipe)
__device__ __forceinline__ float xmax32(float v) {
  u32x2 r = __builtin_amdgcn_permlane32_swap(__float_as_uint(v), __float_as_uint(v), false, false);
  return fmaxf(__uint_as_float(r[0]), __uint_as_float(r[1]));
}
__device__ __forceinline__ float xsum32(float v) {
  u32x2 r = __builtin_amdgcn_permlane32_swap(__float_as_uint(v), __float_as_uint(v), false, false);
  return __uint_as_float(r[0]) + __uint_as_float(r[1]);
}

union ABu { u16x8v u; bf16x8 b; };
union PAu { u32 w[4]; f16x8 v; };

// ---- Kernel A: Wh/Wl[w][out][in] = split-bf16 of W_w[in][out] ----
__global__ void wt_kernel(const float* __restrict__ Wq, const float* __restrict__ Wk,
                          const float* __restrict__ Wv, u16* __restrict__ Wh,
                          u16* __restrict__ Wl) {
  int w = blockIdx.x >> 4;
  int chunk = blockIdx.x & 15;
  const float* W = (w == 0) ? Wq : (w == 1) ? Wk : Wv;
  int t = threadIdx.x;
  int o = chunk * 16 + (t & 15);
  int i0 = (t >> 4) * 16;
  u16x8v h0, h1, l0, l1;
  #pragma unroll
  for (int ii = 0; ii < 8; ++ii) {
    float v0 = W[(size_t)(i0 + ii) * 256 + o];
    u16 h = f2bf(v0); h0[ii] = h; l0[ii] = f2bf(v0 - bf2f(h));
    float v1 = W[(size_t)(i0 + 8 + ii) * 256 + o];
    h = f2bf(v1); h1[ii] = h; l1[ii] = f2bf(v1 - bf2f(h));
  }
  size_t base = (size_t)w * 65536 + (size_t)o * 256 + i0;
  *(u16x8v*)(Wh + base) = h0; *(u16x8v*)(Wh + base + 8) = h1;
  *(u16x8v*)(Wl + base) = l0; *(u16x8v*)(Wl + base + 8) = l1;
}

// ---- Kernel B: QKV projection (fp32-exact 3-pass bf16), W slices staged in LDS ----
// Q pre-scaled by log2(e). V written in PV-fragment-coalesced tiling:
//   Vw[b][s>>4][d][s&15]  (f16) -> a PV B-fragment load is 1KB contiguous.
__global__ __launch_bounds__(256, 2) void proj_kernel(
    const float* __restrict__ x, const float* __restrict__ bq,
    const float* __restrict__ bk, const float* __restrict__ bv,
    const u16* __restrict__ Wh, const u16* __restrict__ Wl,
    f16* __restrict__ Qf, f16* __restrict__ Kf, f16* __restrict__ Vw) {
  __shared__ __align__(16) char Whs[16384];   // [256 out-rows][32 in] bf16, swizzled
  __shared__ __align__(16) char Wls[16384];

  int m = blockIdx.x, w = blockIdx.y;
  int tid = threadIdx.x, lane = tid & 63, wv = tid >> 6;
  int r = lane & 15, c = lane >> 4;
  int row0 = m * 128 + wv * 32;
  const char* Whw = (const char*)(Wh + (size_t)w * 65536);
  const char* Wlw = (const char*)(Wl + (size_t)w * 65536);
  const float* bias = (w == 0) ? bq : (w == 1) ? bk : bv;

  f32x4 acc[2][16];
  #pragma unroll
  for (int g = 0; g < 2; ++g)
    #pragma unroll
    for (int n = 0; n < 16; ++n) acc[g][n] = (f32x4)0.0f;

  for (int ks = 0; ks < 8; ++ks) {
    if (ks) __syncthreads();
    #pragma unroll
    for (int ss = 0; ss < 4; ++ss) {
      int slot = ss * 256 + tid;
      int row = slot >> 2, c4 = slot & 3;
      int dby = (c4 << 4) ^ (((row >> 1) & 3) << 4);
      const char* gh = Whw + (size_t)row * 512 + ks * 64 + dby;
      const char* gl = Wlw + (size_t)row * 512 + ks * 64 + dby;
      __builtin_amdgcn_global_load_lds(
          (const __attribute__((address_space(1))) void*)gh,
          (__attribute__((address_space(3))) void*)(Whs + slot * 16), 16, 0, 0);
      __builtin_amdgcn_global_load_lds(
          (const __attribute__((address_space(1))) void*)gl,
          (__attribute__((address_space(3))) void*)(Wls + slot * 16), 16, 0, 0);
    }
    __syncthreads();

    ABu ah[2], al[2];
    #pragma unroll
    for (int g = 0; g < 2; ++g) {
      const float* xrow = x + (size_t)(row0 + g * 16 + r) * 256 + ks * 32 + c * 8;
      float4 a0 = *(const float4*)(xrow);
      float4 a1 = *(const float4*)(xrow + 4);
      float xv[8] = {a0.x, a0.y, a0.z, a0.w, a1.x, a1.y, a1.z, a1.w};
      #pragma unroll
      for (int j = 0; j < 8; ++j) {
        u16 h = f2bf(xv[j]);
        ah[g].u[j] = h;
        al[g].u[j] = f2bf(xv[j] - bf2f(h));
      }
    }
    #pragma unroll
    for (int n = 0; n < 16; ++n) {
      int wrow = n * 16 + r;
      int wof = (c * 16) ^ (((wrow >> 1) & 3) << 4);
      bf16x8 whf = *(const bf16x8*)(Whs + wrow * 64 + wof);
      bf16x8 wlf = *(const bf16x8*)(Wls + wrow * 64 + wof);
      #pragma unroll
      for (int g = 0; g < 2; ++g) {
        acc[g][n] = __builtin_amdgcn_mfma_f32_16x16x32_bf16(ah[g].b, whf, acc[g][n], 0, 0, 0);
        acc[g][n] = __builtin_amdgcn_mfma_f32_16x16x32_bf16(al[g].b, whf, acc[g][n], 0, 0, 0);
        acc[g][n] = __builtin_amdgcn_mfma_f32_16x16x32_bf16(ah[g].b, wlf, acc[g][n], 0, 0, 0);
      }
    }
  }

  if (w < 2) {
    f16* outp = (w == 0) ? Qf : Kf;
    float osc = (w == 0) ? LOG2E : 1.0f;   // exp2-domain scores
    #pragma unroll
    for (int g = 0; g < 2; ++g)
      #pragma unroll
      for (int n = 0; n < 16; ++n) {
        int col = n * 16 + r;
        float bb = bias[col];
        #pragma unroll
        for (int i = 0; i < 4; ++i) {
          float v = fmaxf(acc[g][n][i] + bb, 0.0f) * osc;
          outp[(size_t)(row0 + g * 16 + c * 4 + i) * 256 + col] = (f16)v;
        }
      }
  } else {
    #pragma unroll
    for (int g = 0; g < 2; ++g) {
      int grow = row0 + g * 16 + c * 4;
      int b = grow >> 12, s0 = grow & 4095;
      int kb = s0 >> 4, k16 = s0 & 15;       // s0 % 16 in {0,4,8,12}
      #pragma unroll
      for (int n = 0; n < 16; ++n) {
        int d = n * 16 + r;
        float bb = bias[d];
        f16x4 pk;
        #pragma unroll
        for (int i = 0; i < 4; ++i) pk[i] = (f16)(acc[g][n][i] + bb);
        *(f16x4*)(Vw + (((size_t)b * 256 + kb) * 256 + d) * 16 + k16) = pk;
      }
    }
  }
}

// ---- Kernel C: flash attention, V direct-from-L2 ----
// 256 blocks x 8 waves (512 thr), 32 q-rows/wave, KVBLK=32, splitK=4.
// K in LDS (dbuf 2x16KB = 32KB only); V fragments buffer-loaded straight from
// the tiled Vw layout (1KB contiguous per wave-instruction, VMEM pipe, no
// barrier dependency, compiler-tracked waits). Removes half the LDS traffic
// and the entire V staging path.
__global__ __launch_bounds__(512, 2) void attn_kernel(
    const f16* __restrict__ Qf, const f16* __restrict__ Kf,
    const f16* __restrict__ Vw, f16* __restrict__ Opart, float* __restrict__ Ml) {
  __shared__ __align__(16) char Ksm[2][16384];   // [32 keys][256 d] f16, swizzled

  int bid = blockIdx.x;
  int xcd = bid & 7;                    // pin (batch, kq-pair) per XCD for L2 reuse
  int batch = xcd >> 1;
  int kq = ((xcd & 1) << 1) | ((bid >> 3) & 1);
  int qtl = bid >> 4;                   // 0..15
  int tid = threadIdx.x, lane = tid & 63, wv = tid >> 6;   // wv 0..7
  int ln = lane & 31, hi = lane >> 5;
  int q0 = qtl * 256 + wv * 32;
  int kv0 = kq * 1024;

  // Q B-fragments: qf[ks] elem j = Q[q0+ln][ks*16 + hi*8 + j]
  f16x8 qf[16];
  {
    const f16* qp = Qf + ((size_t)(batch * 4096 + q0 + ln)) * 256 + hi * 8;
    #pragma unroll
    for (int ks = 0; ks < 16; ++ks) qf[ks] = *(const f16x8*)(qp + ks * 16);
  }

  f32x16 O[8];
  #pragma unroll
  for (int dt = 0; dt < 8; ++dt) O[dt] = (f32x16)0.0f;
  float m_ = -1.0e30f, l_ = 0.0f;

  const char* Kbase = (const char*)(Kf + ((size_t)(batch * 4096 + kv0)) * 256);
  // V fragment base for this lane: Vw[batch][kb][d=dt*32+ln][hi*8 ..]
  const f16* Vlane = Vw + ((size_t)batch * 256 * 256) * 16 + (size_t)ln * 16 + hi * 8;

#define STAGE(T, BF)                                                           \
  {                                                                            \
    _Pragma("unroll")                                                          \
    for (int rr = 0; rr < 2; ++rr) {                                           \
      int slot = rr * 512 + tid;                                               \
      int krow = slot >> 5;                                                    \
      int dby = ((slot & 31) << 4) ^ ((krow & 7) << 4);                        \
      const char* g = Kbase + (size_t)((T) * 32 + krow) * 512 + dby;           \
      __builtin_amdgcn_global_load_lds(                                        \
          (const __attribute__((address_space(1))) void*)g,                    \
          (__attribute__((address_space(3))) void*)(Ksm[BF] + slot * 16), 16, 0, 0); \
    }                                                                          \
  }

  int kswz = (ln & 7) << 4;
  int hi16 = hi * 16;

  STAGE(0, 0);

  for (int t = 0; t < 32; ++t) {
    __builtin_amdgcn_s_barrier();            // all reads of buffer (t+1)&1 done
    if (t < 31) {
      STAGE(t + 1, (t + 1) & 1);
      // outstanding (this wave): [K(t):2][K(t+1):2] (+ any long-done V) ->
      // vmcnt(2) leaves only the newest 2 = K(t+1); K(t) is guaranteed landed.
      asm volatile("s_waitcnt vmcnt(2)" ::: "memory");
    } else {
      asm volatile("s_waitcnt vmcnt(0)" ::: "memory");
    }
    __builtin_amdgcn_sched_barrier(0);
    __builtin_amdgcn_s_barrier();            // K(t) visible to all waves

    const char* Kc = Ksm[t & 1];
    // V fragment prefetch, k2=0 half (keys kv+0..15): issued now, consumed
    // after softmax -> latency hidden under QK + softmax. Compiler tracks.
    size_t vrow0 = ((size_t)(kq * 64 + t * 2) * 256) * 16;
    f16x8 vA[8];
    #pragma unroll
    for (int dt = 0; dt < 8; ++dt)
      vA[dt] = *(const f16x8*)(Vlane + vrow0 + (size_t)dt * 512);   // 32 d * 16 elems

    // ---- QK: S^T = K Q^T (32 keys x 32 q) ----
    f32x16 sA = (f32x16)0.0f;
    __builtin_amdgcn_s_setprio(1);
    #pragma unroll
    for (int ks = 0; ks < 16; ++ks) {
      f16x8 kf = *(const f16x8*)(Kc + ln * 512 + ((ks * 32 + hi16) ^ kswz));
      sA = __builtin_amdgcn_mfma_f32_32x32x16_f16(kf, qf[ks], sA, 0, 0, 0);
    }
    __builtin_amdgcn_s_setprio(0);

    // ---- softmax (exp2 domain, lane-local rows, defer-max) ----
    float pm = fmaxf(
        fmaxf(fmaxf(fmaxf(sA[0], sA[1]), fmaxf(sA[2], sA[3])),
              fmaxf(fmaxf(sA[4], sA[5]), fmaxf(sA[6], sA[7]))),
        fmaxf(fmaxf(fmaxf(sA[8], sA[9]), fmaxf(sA[10], sA[11])),
              fmaxf(fmaxf(sA[12], sA[13]), fmaxf(sA[14], sA[15]))));
    pm = xmax32(pm);
    if (!__all(pm <= m_ + 11.5416f)) {       // THR = 8 nats in log2 domain
      float mn = fmaxf(m_, pm);
      float sc = exp2f(m_ - mn);
      m_ = mn; l_ *= sc;
      #pragma unroll
      for (int rg = 0; rg < 16; ++rg) {
        float srg = __shfl(sc, (rg & 3) + 8 * (rg >> 2) + 4 * hi);
        #pragma unroll
        for (int dt = 0; dt < 8; ++dt) O[dt][rg] *= srg;
      }
    }
    float p_[16];
    #pragma unroll
    for (int j = 0; j < 16; ++j) p_[j] = exp2f(sA[j] - m_);
    float ps = (((p_[0] + p_[1]) + (p_[2] + p_[3])) +
                ((p_[4] + p_[5]) + (p_[6] + p_[7]))) +
               (((p_[8] + p_[9]) + (p_[10] + p_[11])) +
                ((p_[12] + p_[13]) + (p_[14] + p_[15])));
    l_ += xsum32(ps);

    PAu pa0, pa1;
    {
      u32x2 r1 = __builtin_amdgcn_permlane32_swap(pkrtz(p_[0], p_[1]), pkrtz(p_[4], p_[5]), false, false);
      u32x2 r2 = __builtin_amdgcn_permlane32_swap(pkrtz(p_[2], p_[3]), pkrtz(p_[6], p_[7]), false, false);
      pa0.w[0] = r1[0]; pa0.w[1] = r2[0]; pa0.w[2] = r1[1]; pa0.w[3] = r2[1];
      u32x2 r3 = __builtin_amdgcn_permlane32_swap(pkrtz(p_[8], p_[9]), pkrtz(p_[12], p_[13]), false, false);
      u32x2 r4 = __builtin_amdgcn_permlane32_swap(pkrtz(p_[10], p_[11]), pkrtz(p_[14], p_[15]), false, false);
      pa1.w[0] = r3[0]; pa1.w[1] = r4[0]; pa1.w[2] = r3[1]; pa1.w[3] = r4[1];
    }

    // ---- PV: O += P V (V from registers; k2=1 prefetched mid-stream) ----
    __builtin_amdgcn_s_setprio(1);
    #pragma unroll
    for (int dt = 0; dt < 4; ++dt)
      O[dt] = __builtin_amdgcn_mfma_f32_32x32x16_f16(pa0.v, vA[dt], O[dt], 0, 0, 0);
    __builtin_amdgcn_s_setprio(0);
    f16x8 vB[8];                              // k2=1 half (keys kv+16..31)
    #pragma unroll
    for (int dt = 0; dt < 8; ++dt)
      vB[dt] = *(const f16x8*)(Vlane + vrow0 + 4096 + (size_t)dt * 512);
    __builtin_amdgcn_s_setprio(1);
    #pragma unroll
    for (int dt = 4; dt < 8; ++dt)
      O[dt] = __builtin_amdgcn_mfma_f32_32x32x16_f16(pa0.v, vA[dt], O[dt], 0, 0, 0);
    #pragma unroll
    for (int dt = 0; dt < 8; ++dt)
      O[dt] = __builtin_amdgcn_mfma_f32_32x32x16_f16(pa1.v, vB[dt], O[dt], 0, 0, 0);
    __builtin_amdgcn_s_setprio(0);
  }

  // epilogue: store NORMALIZED O (f16-safe), plus (m,l) per q-row
  float invl = 1.0f / l_;
  #pragma unroll
  for (int rg = 0; rg < 16; ++rg) {
    int qr = (rg & 3) + 8 * (rg >> 2) + 4 * hi;
    float iv = __shfl(invl, qr);
    size_t row = (size_t)kq * 16384 + batch * 4096 + q0 + qr;
    #pragma unroll
    for (int dt = 0; dt < 8; ++dt)
      Opart[row * 256 + dt * 32 + ln] = (f16)(O[dt][rg] * iv);
  }
  if (hi == 0) {
    size_t grow = (size_t)kq * 16384 + batch * 4096 + q0 + ln;
    Ml[grow * 2] = m_;
    Ml[grow * 2 + 1] = l_;
  }
#undef STAGE
}

// ---- Kernel D: split-K merge (m stored in log2 domain -> exp2 weights) ----
__global__ __launch_bounds__(256) void merge_kernel(
    const f16* __restrict__ Opart, const float* __restrict__ Ml,
    float* __restrict__ out) {
  int gid = blockIdx.x * 256 + threadIdx.x;
  int row = gid >> 5, d0 = (gid & 31) * 8;
  float m[4], l[4];
  #pragma unroll
  for (int p = 0; p < 4; ++p) {
    m[p] = Ml[((size_t)p * 16384 + row) * 2];
    l[p] = Ml[((size_t)p * 16384 + row) * 2 + 1];
  }
  float M = fmaxf(fmaxf(m[0], m[1]), fmaxf(m[2], m[3]));
  float wl[4], L = 0.f;
  #pragma unroll
  for (int p = 0; p < 4; ++p) { wl[p] = exp2f(m[p] - M) * l[p]; L += wl[p]; }
  float o[8] = {0.f, 0.f, 0.f, 0.f, 0.f, 0.f, 0.f, 0.f};
  #pragma unroll
  for (int p = 0; p < 4; ++p) {
    f16x8 v = *(const f16x8*)(Opart + ((size_t)p * 16384 + row) * 256 + d0);
    #pragma unroll
    for (int j = 0; j < 8; ++j) o[j] += wl[p] * (float)v[j];
  }
  float invL = 1.0f / L;
  float4 o0 = {o[0] * invL, o[1] * invL, o[2] * invL, o[3] * invL};
  float4 o1 = {o[4] * invL, o[5] * invL, o[6] * invL, o[7] * invL};
  *(float4*)(out + (size_t)row * 256 + d0) = o0;
  *(float4*)(out + (size_t)row * 256 + d0 + 4) = o1;
}

extern "C" void kernel_launch(void* const* d_in, const int* in_sizes, int n_in,
                              void* d_out, int out_size, void* d_ws, size_t ws_size,
                              hipStream_t stream) {
  const float* x  = (const float*)d_in[0];
  const float* Wq = (const float*)d_in[1];
  const float* bq = (const float*)d_in[2];
  const float* Wk = (const float*)d_in[3];
  const float* bk = (const float*)d_in[4];
  const float* Wv = (const float*)d_in[5];
  const float* bv = (const float*)d_in[6];
  float* out = (float*)d_out;

  u16* Wh = (u16*)d_ws;
  u16* Wl = Wh + 3 * 65536;
  f16* Qf = (f16*)(Wl + 3 * 65536);
  f16* Kf = Qf + (size_t)16384 * 256;
  f16* Vw = Kf + (size_t)16384 * 256;
  f16* Opart = Vw + (size_t)4 * 256 * 4096;
  float* Ml = (float*)(Opart + (size_t)4 * 16384 * 256);

  wt_kernel<<<48, 256, 0, stream>>>(Wq, Wk, Wv, Wh, Wl);
  proj_kernel<<<dim3(128, 3), 256, 0, stream>>>(x, bq, bk, bv, Wh, Wl, Qf, Kf, Vw);
  attn_kernel<<<256, 512, 0, stream>>>(Qf, Kf, Vw, Opart, Ml);
  merge_kernel<<<2048, 256, 0, stream>>>(Opart, Ml, out);
}

// Round 11
// 194.904 us; speedup vs baseline: 1.0196x; 1.0196x over previous
//
#include <hip/hip_runtime.h>
#include <stdint.h>

typedef __bf16 bf16;
typedef bf16 bf16x8 __attribute__((ext_vector_type(8)));
typedef _Float16 f16;
typedef f16 f16x8 __attribute__((ext_vector_type(8)));
typedef f16 f16x4 __attribute__((ext_vector_type(4)));
typedef float f32x4 __attribute__((ext_vector_type(4)));
typedef float f32x16 __attribute__((ext_vector_type(16)));
typedef unsigned short u16;
typedef unsigned int u32;
typedef u32 u32x2 __attribute__((ext_vector_type(2)));
typedef u16 u16x8v __attribute__((ext_vector_type(8)));

#define LOG2E 1.44269504088896340736f

__device__ __forceinline__ u16 f2bf(float f) {
  u32 u = __float_as_uint(f);
  u32 r = u + 0x7fffu + ((u >> 16) & 1u);
  return (u16)(r >> 16);
}
__device__ __forceinline__ float bf2f(u16 h) { return __uint_as_float(((u32)h) << 16); }

__device__ __forceinline__ u32 pkrtz(float a, float b) {
  auto r = __builtin_amdgcn_cvt_pkrtz(a, b);   // f16x2: a->[15:0], b->[31:16]
  u32 u; __builtin_memcpy(&u, &r, 4);
  return u;
}
// cross-32 reduce helpers via permlane32_swap (VALU, no LDS pipe)
__device__ __forceinline__ float xmax32(float v) {
  u32x2 r = __builtin_amdgcn_permlane32_swap(__float_as_uint(v), __float_as_uint(v), false, false);
  return fmaxf(__uint_as_float(r[0]), __uint_as_float(r[1]));
}
__device__ __forceinline__ float xsum32(float v) {
  u32x2 r = __builtin_amdgcn_permlane32_swap(__float_as_uint(v), __float_as_uint(v), false, false);
  return __uint_as_float(r[0]) + __uint_as_float(r[1]);
}

union ABu { u16x8v u; bf16x8 b; };
union PAu { u32 w[4]; f16x8 v; };

// ---- Kernel A: Wh/Wl[w][out][in] = split-bf16 of W_w[in][out] ----
__global__ void wt_kernel(const float* __restrict__ Wq, const float* __restrict__ Wk,
                          const float* __restrict__ Wv, u16* __restrict__ Wh,
                          u16* __restrict__ Wl) {
  int w = blockIdx.x >> 4;
  int chunk = blockIdx.x & 15;
  const float* W = (w == 0) ? Wq : (w == 1) ? Wk : Wv;
  int t = threadIdx.x;
  int o = chunk * 16 + (t & 15);
  int i0 = (t >> 4) * 16;
  u16x8v h0, h1, l0, l1;
  #pragma unroll
  for (int ii = 0; ii < 8; ++ii) {
    float v0 = W[(size_t)(i0 + ii) * 256 + o];
    u16 h = f2bf(v0); h0[ii] = h; l0[ii] = f2bf(v0 - bf2f(h));
    float v1 = W[(size_t)(i0 + 8 + ii) * 256 + o];
    h = f2bf(v1); h1[ii] = h; l1[ii] = f2bf(v1 - bf2f(h));
  }
  size_t base = (size_t)w * 65536 + (size_t)o * 256 + i0;
  *(u16x8v*)(Wh + base) = h0; *(u16x8v*)(Wh + base + 8) = h1;
  *(u16x8v*)(Wl + base) = l0; *(u16x8v*)(Wl + base + 8) = l1;
}

// ---- Kernel B: QKV projection (fp32-exact 3-pass bf16), W slices staged in LDS ----
// Q output is pre-scaled by log2(e) so attention softmax runs in exp2 domain.
__global__ __launch_bounds__(256, 2) void proj_kernel(
    const float* __restrict__ x, const float* __restrict__ bq,
    const float* __restrict__ bk, const float* __restrict__ bv,
    const u16* __restrict__ Wh, const u16* __restrict__ Wl,
    f16* __restrict__ Qf, f16* __restrict__ Kf, f16* __restrict__ Vt) {
  __shared__ __align__(16) char Whs[16384];   // [256 out-rows][32 in] bf16, swizzled
  __shared__ __align__(16) char Wls[16384];

  int m = blockIdx.x, w = blockIdx.y;
  int tid = threadIdx.x, lane = tid & 63, wv = tid >> 6;
  int r = lane & 15, c = lane >> 4;
  int row0 = m * 128 + wv * 32;
  const char* Whw = (const char*)(Wh + (size_t)w * 65536);
  const char* Wlw = (const char*)(Wl + (size_t)w * 65536);
  const float* bias = (w == 0) ? bq : (w == 1) ? bk : bv;

  f32x4 acc[2][16];
  #pragma unroll
  for (int g = 0; g < 2; ++g)
    #pragma unroll
    for (int n = 0; n < 16; ++n) acc[g][n] = (f32x4)0.0f;

  for (int ks = 0; ks < 8; ++ks) {
    if (ks) __syncthreads();
    #pragma unroll
    for (int ss = 0; ss < 4; ++ss) {
      int slot = ss * 256 + tid;
      int row = slot >> 2, c4 = slot & 3;
      int dby = (c4 << 4) ^ (((row >> 1) & 3) << 4);
      const char* gh = Whw + (size_t)row * 512 + ks * 64 + dby;
      const char* gl = Wlw + (size_t)row * 512 + ks * 64 + dby;
      __builtin_amdgcn_global_load_lds(
          (const __attribute__((address_space(1))) void*)gh,
          (__attribute__((address_space(3))) void*)(Whs + slot * 16), 16, 0, 0);
      __builtin_amdgcn_global_load_lds(
          (const __attribute__((address_space(1))) void*)gl,
          (__attribute__((address_space(3))) void*)(Wls + slot * 16), 16, 0, 0);
    }
    __syncthreads();

    ABu ah[2], al[2];
    #pragma unroll
    for (int g = 0; g < 2; ++g) {
      const float* xrow = x + (size_t)(row0 + g * 16 + r) * 256 + ks * 32 + c * 8;
      float4 a0 = *(const float4*)(xrow);
      float4 a1 = *(const float4*)(xrow + 4);
      float xv[8] = {a0.x, a0.y, a0.z, a0.w, a1.x, a1.y, a1.z, a1.w};
      #pragma unroll
      for (int j = 0; j < 8; ++j) {
        u16 h = f2bf(xv[j]);
        ah[g].u[j] = h;
        al[g].u[j] = f2bf(xv[j] - bf2f(h));
      }
    }
    #pragma unroll
    for (int n = 0; n < 16; ++n) {
      int wrow = n * 16 + r;
      int wof = (c * 16) ^ (((wrow >> 1) & 3) << 4);
      bf16x8 whf = *(const bf16x8*)(Whs + wrow * 64 + wof);
      bf16x8 wlf = *(const bf16x8*)(Wls + wrow * 64 + wof);
      #pragma unroll
      for (int g = 0; g < 2; ++g) {
        acc[g][n] = __builtin_amdgcn_mfma_f32_16x16x32_bf16(ah[g].b, whf, acc[g][n], 0, 0, 0);
        acc[g][n] = __builtin_amdgcn_mfma_f32_16x16x32_bf16(al[g].b, whf, acc[g][n], 0, 0, 0);
        acc[g][n] = __builtin_amdgcn_mfma_f32_16x16x32_bf16(ah[g].b, wlf, acc[g][n], 0, 0, 0);
      }
    }
  }

  if (w < 2) {
    f16* outp = (w == 0) ? Qf : Kf;
    float osc = (w == 0) ? LOG2E : 1.0f;   // exp2-domain scores
    #pragma unroll
    for (int g = 0; g < 2; ++g)
      #pragma unroll
      for (int n = 0; n < 16; ++n) {
        int col = n * 16 + r;
        float bb = bias[col];
        #pragma unroll
        for (int i = 0; i < 4; ++i) {
          float v = fmaxf(acc[g][n][i] + bb, 0.0f) * osc;
          outp[(size_t)(row0 + g * 16 + c * 4 + i) * 256 + col] = (f16)v;
        }
      }
  } else {
    #pragma unroll
    for (int g = 0; g < 2; ++g) {
      int grow = row0 + g * 16 + c * 4;
      int b = grow >> 12, s0 = grow & 4095;
      #pragma unroll
      for (int n = 0; n < 16; ++n) {
        int d = n * 16 + r;
        float bb = bias[d];
        f16x4 pk;
        #pragma unroll
        for (int i = 0; i < 4; ++i) pk[i] = (f16)(acc[g][n][i] + bb);
        *(f16x4*)(Vt + (size_t)(b * 256 + d) * 4096 + s0) = pk;
      }
    }
  }
}

// ---- Kernel C: flash attention, softmax woven into MFMA streams ----
// 256 blocks x 8 waves, 32 q-rows/wave, KVBLK=64, splitK=4, K/V dbuf (128KB).
// Round 0 is peeled with MAX-FIRST softmax to seed m_ (pre-branch exp2 with an
// unseeded m_ overflows f32 -> inf -> NaN; seeded gaps are <= ~65 log2, safe).
// Rounds 1..15: QK(A); QK(B)~sm(A); finish(A); PV(A)~sm(B); finish(B); PV(B).
__global__ __launch_bounds__(512, 2) void attn_kernel(
    const f16* __restrict__ Qf, const f16* __restrict__ Kf,
    const f16* __restrict__ Vt, f16* __restrict__ Opart, float* __restrict__ Ml) {
  __shared__ __align__(16) char Ksm[2][32768];   // [64 keys][256 d] f16, swizzled
  __shared__ __align__(16) char Vsm[2][32768];   // [256 d][64 keys] f16, swizzled

  int bid = blockIdx.x;
  int xcd = bid & 7;
  int batch = xcd >> 1;
  int kq = ((xcd & 1) << 1) | ((bid >> 3) & 1);
  int qtl = bid >> 4;
  int tid = threadIdx.x, lane = tid & 63, wv = tid >> 6;
  int ln = lane & 31, hi = lane >> 5;
  int q0 = qtl * 256 + wv * 32;
  int kv0 = kq * 1024;

  f16x8 qf[16];
  {
    const f16* qp = Qf + ((size_t)(batch * 4096 + q0 + ln)) * 256 + hi * 8;
    #pragma unroll
    for (int ks = 0; ks < 16; ++ks) qf[ks] = *(const f16x8*)(qp + ks * 16);
  }

  f32x16 O[8];
  #pragma unroll
  for (int dt = 0; dt < 8; ++dt) O[dt] = (f32x16)0.0f;
  float m_ = 0.0f, l_ = 0.0f;      // m_ is properly seeded by the peeled round 0

  const char* Kbase = (const char*)(Kf + ((size_t)(batch * 4096 + kv0)) * 256);
  const char* Vbase = (const char*)(Vt + (size_t)batch * 1048576 + kv0);

#define STAGE(T, BF)                                                           \
  {                                                                            \
    _Pragma("unroll")                                                          \
    for (int rr = 0; rr < 4; ++rr) {                                           \
      int slot = rr * 512 + tid;                                               \
      int krow = slot >> 5;                                                    \
      int dby = ((slot & 31) << 4) ^ ((krow & 7) << 4);                        \
      const char* g = Kbase + (size_t)((T) * 64 + krow) * 512 + dby;           \
      __builtin_amdgcn_global_load_lds(                                        \
          (const __attribute__((address_space(1))) void*)g,                    \
          (__attribute__((address_space(3))) void*)(Ksm[BF] + slot * 16), 16, 0, 0); \
    }                                                                          \
    _Pragma("unroll")                                                          \
    for (int rr = 0; rr < 4; ++rr) {                                           \
      int slot = rr * 512 + tid;                                               \
      int vrow = slot >> 3;                                                    \
      int dby = ((slot & 7) << 4) ^ ((vrow & 7) << 4);                         \
      const char* g = Vbase + (size_t)vrow * 8192 + (T) * 128 + dby;           \
      __builtin_amdgcn_global_load_lds(                                        \
          (const __attribute__((address_space(1))) void*)g,                    \
          (__attribute__((address_space(3))) void*)(Vsm[BF] + slot * 16), 16, 0, 0); \
    }                                                                          \
  }

  int kswz = (ln & 7) << 4;
  int vswz = (ln & 7) << 4;
  int hi16 = hi * 16;

#define QKS(SACC, KO, ks)                                                      \
  { f16x8 kf = *(const f16x8*)(Kc + ((KO) + ln) * 512 + (((ks) * 32 + hi16) ^ kswz)); \
    SACC = __builtin_amdgcn_mfma_f32_32x32x16_f16(kf, qf[ks], SACC, 0, 0, 0); }
#define PVS(PA, dt, VO)                                                        \
  { f16x8 vf = *(const f16x8*)(Vc + ((dt) * 32 + ln) * 128 + (((VO) + hi16) ^ vswz)); \
    O[dt] = __builtin_amdgcn_mfma_f32_32x32x16_f16(PA, vf, O[dt], 0, 0, 0); }
  // row-max of 16 accumulator elems + cross-pair reduce
#define ROWMAX(S, PM)                                                          \
  float PM;                                                                    \
  { float z0 = fmaxf(fmaxf(S[0], S[1]), fmaxf(S[2], S[3]));                    \
    float z1 = fmaxf(fmaxf(S[4], S[5]), fmaxf(S[6], S[7]));                    \
    float z2 = fmaxf(fmaxf(S[8], S[9]), fmaxf(S[10], S[11]));                  \
    float z3 = fmaxf(fmaxf(S[12], S[13]), fmaxf(S[14], S[15]));                \
    PM = xmax32(fmaxf(fmaxf(z0, z1), fmaxf(z2, z3))); }
  // in-place exp2 of 4 elems (current m_), accumulating partial row-sum
#define SM_EXP(S, j0, PS)                                                      \
  { S[j0] = exp2f(S[j0] - m_); S[(j0)+1] = exp2f(S[(j0)+1] - m_);              \
    S[(j0)+2] = exp2f(S[(j0)+2] - m_); S[(j0)+3] = exp2f(S[(j0)+3] - m_);      \
    PS += ((S[j0] + S[(j0)+1]) + (S[(j0)+2] + S[(j0)+3])); }
  // P (already exp'd) -> two PV A-fragments
#define P2FRAG(S, PA0, PA1)                                                    \
  { u32x2 r1 = __builtin_amdgcn_permlane32_swap(pkrtz(S[0], S[1]), pkrtz(S[4], S[5]), false, false); \
    u32x2 r2 = __builtin_amdgcn_permlane32_swap(pkrtz(S[2], S[3]), pkrtz(S[6], S[7]), false, false); \
    PA0.w[0] = r1[0]; PA0.w[1] = r2[0]; PA0.w[2] = r1[1]; PA0.w[3] = r2[1];    \
    u32x2 r3 = __builtin_amdgcn_permlane32_swap(pkrtz(S[8], S[9]), pkrtz(S[12], S[13]), false, false); \
    u32x2 r4 = __builtin_amdgcn_permlane32_swap(pkrtz(S[10], S[11]), pkrtz(S[14], S[15]), false, false); \
    PA1.w[0] = r3[0]; PA1.w[1] = r4[0]; PA1.w[2] = r3[1]; PA1.w[3] = r4[1]; }
  // rescale fixup (rare) + l_ update + fragment conversion
#define SM_FINISH(S, PM, PS, PA0, PA1)                                         \
  if (!__all((PM) <= m_ + 11.5416f)) {                                         \
    float mn = fmaxf(m_, (PM));                                                \
    float sc = exp2f(m_ - mn);                                                 \
    m_ = mn; l_ *= sc; (PS) *= sc;                                             \
    _Pragma("unroll")                                                          \
    for (int j = 0; j < 16; ++j) S[j] *= sc;                                   \
    _Pragma("unroll")                                                          \
    for (int rg = 0; rg < 16; ++rg) {                                          \
      float srg = __shfl(sc, (rg & 3) + 8 * (rg >> 2) + 4 * hi);               \
      _Pragma("unroll")                                                        \
      for (int dt = 0; dt < 8; ++dt) O[dt][rg] *= srg;                         \
    }                                                                          \
  }                                                                            \
  l_ += xsum32(PS);                                                            \
  P2FRAG(S, PA0, PA1)

  STAGE(0, 0);

  // ================= peeled round 0 (max-first softmax seeds m_) ============
  {
    __builtin_amdgcn_s_barrier();
    STAGE(1, 1);
    asm volatile("s_waitcnt vmcnt(8)" ::: "memory");
    __builtin_amdgcn_sched_barrier(0);
    __builtin_amdgcn_s_barrier();

    const char* Kc = Ksm[0];
    const char* Vc = Vsm[0];

    f32x16 sAa = (f32x16)0.0f;
    f32x16 sAb = (f32x16)0.0f;
    __builtin_amdgcn_s_setprio(1);
    #pragma unroll
    for (int ks = 0; ks < 16; ++ks) QKS(sAa, 0, ks);
    #pragma unroll
    for (int ks = 0; ks < 16; ++ks) QKS(sAb, 32, ks);
    __builtin_amdgcn_s_setprio(0);

    // max-first softmax(A): seed m_
    ROWMAX(sAa, pmA);
    m_ = pmA;
    float psA = 0.0f;
    SM_EXP(sAa, 0, psA); SM_EXP(sAa, 4, psA);
    SM_EXP(sAa, 8, psA); SM_EXP(sAa, 12, psA);
    l_ = xsum32(psA);
    PAu paA0, paA1;
    P2FRAG(sAa, paA0, paA1);

    // PV(A)
    __builtin_amdgcn_s_setprio(1);
    #pragma unroll
    for (int ks = 0; ks < 16; ++ks) {
      int dt = ks >> 1, k2 = ks & 1;
      PVS(k2 ? paA1.v : paA0.v, dt, k2 * 32);
    }
    __builtin_amdgcn_s_setprio(0);

    // softmax(B): m_ now seeded -> pre-branch exp is safe
    ROWMAX(sAb, pmB);
    float psB = 0.0f;
    SM_EXP(sAb, 0, psB); SM_EXP(sAb, 4, psB);
    SM_EXP(sAb, 8, psB); SM_EXP(sAb, 12, psB);
    PAu paB0, paB1;
    SM_FINISH(sAb, pmB, psB, paB0, paB1);

    // PV(B)
    __builtin_amdgcn_s_setprio(1);
    #pragma unroll
    for (int ks = 0; ks < 16; ++ks) {
      int dt = ks >> 1, k2 = ks & 1;
      PVS(k2 ? paB1.v : paB0.v, dt, 64 + k2 * 32);
    }
    __builtin_amdgcn_s_setprio(0);
  }

  // ================= rounds 1..15 (woven schedule) ==========================
  for (int t = 1; t < 16; ++t) {
    __builtin_amdgcn_s_barrier();            // all reads of buffer (t+1)&1 done
    if (t < 15) {
      STAGE(t + 1, (t + 1) & 1);
      asm volatile("s_waitcnt vmcnt(8)" ::: "memory");   // stage(t) landed
    } else {
      asm volatile("s_waitcnt vmcnt(0)" ::: "memory");
    }
    __builtin_amdgcn_sched_barrier(0);
    __builtin_amdgcn_s_barrier();            // stage(t) visible to all waves

    const char* Kc = Ksm[t & 1];
    const char* Vc = Vsm[t & 1];

    // ---- phase 1: QK(A), keys [0,32) ----
    f32x16 sAa = (f32x16)0.0f;
    __builtin_amdgcn_s_setprio(1);
    #pragma unroll
    for (int ks = 0; ks < 16; ++ks) QKS(sAa, 0, ks);

    // ---- phase 2: QK(B) keys [32,64) woven with softmax(A) pre-branch ----
    f32x16 sAb = (f32x16)0.0f;
    float psA = 0.0f;
    QKS(sAb, 32, 0); QKS(sAb, 32, 1);
    float a0 = fmaxf(sAa[0], sAa[1]), a1 = fmaxf(sAa[2], sAa[3]);
    QKS(sAb, 32, 2); QKS(sAb, 32, 3);
    float a2 = fmaxf(sAa[4], sAa[5]), a3 = fmaxf(sAa[6], sAa[7]);
    QKS(sAb, 32, 4); QKS(sAb, 32, 5);
    float a4 = fmaxf(sAa[8], sAa[9]), a5 = fmaxf(sAa[10], sAa[11]);
    QKS(sAb, 32, 6); QKS(sAb, 32, 7);
    float a6 = fmaxf(sAa[12], sAa[13]), a7 = fmaxf(sAa[14], sAa[15]);
    QKS(sAb, 32, 8);
    a0 = fmaxf(fmaxf(a0, a1), fmaxf(a2, a3));
    QKS(sAb, 32, 9);
    a4 = fmaxf(fmaxf(a4, a5), fmaxf(a6, a7));
    QKS(sAb, 32, 10);
    float pmA = xmax32(fmaxf(a0, a4));
    QKS(sAb, 32, 11);
    SM_EXP(sAa, 0, psA);
    QKS(sAb, 32, 12);
    SM_EXP(sAa, 4, psA);
    QKS(sAb, 32, 13);
    SM_EXP(sAa, 8, psA);
    QKS(sAb, 32, 14);
    SM_EXP(sAa, 12, psA);
    QKS(sAb, 32, 15);
    __builtin_amdgcn_s_setprio(0);
    PAu paA0, paA1;
    SM_FINISH(sAa, pmA, psA, paA0, paA1);

    // ---- phase 3: PV(A) (V bytes 0/32) woven with softmax(B) pre-branch ----
    float psB = 0.0f;
    __builtin_amdgcn_s_setprio(1);
    PVS(paA0.v, 0, 0); PVS(paA1.v, 0, 32);
    float b0 = fmaxf(sAb[0], sAb[1]), b1 = fmaxf(sAb[2], sAb[3]);
    PVS(paA0.v, 1, 0); PVS(paA1.v, 1, 32);
    float b2 = fmaxf(sAb[4], sAb[5]), b3 = fmaxf(sAb[6], sAb[7]);
    PVS(paA0.v, 2, 0); PVS(paA1.v, 2, 32);
    float b4 = fmaxf(sAb[8], sAb[9]), b5 = fmaxf(sAb[10], sAb[11]);
    PVS(paA0.v, 3, 0); PVS(paA1.v, 3, 32);
    float b6 = fmaxf(sAb[12], sAb[13]), b7 = fmaxf(sAb[14], sAb[15]);
    PVS(paA0.v, 4, 0); PVS(paA1.v, 4, 32);
    b0 = fmaxf(fmaxf(b0, b1), fmaxf(b2, b3));
    b4 = fmaxf(fmaxf(b4, b5), fmaxf(b6, b7));
    PVS(paA0.v, 5, 0);
    float pmB = xmax32(fmaxf(b0, b4));
    PVS(paA1.v, 5, 32);
    SM_EXP(sAb, 0, psB);
    PVS(paA0.v, 6, 0);
    SM_EXP(sAb, 4, psB);
    PVS(paA1.v, 6, 32);
    SM_EXP(sAb, 8, psB);
    PVS(paA0.v, 7, 0);
    SM_EXP(sAb, 12, psB);
    PVS(paA1.v, 7, 32);
    __builtin_amdgcn_s_setprio(0);
    PAu paB0, paB1;
    SM_FINISH(sAb, pmB, psB, paB0, paB1);

    // ---- phase 4: PV(B) (V bytes 64/96) ----
    __builtin_amdgcn_s_setprio(1);
    #pragma unroll
    for (int ks = 0; ks < 16; ++ks) {
      int dt = ks >> 1, k2 = ks & 1;
      PVS(k2 ? paB1.v : paB0.v, dt, 64 + k2 * 32);
    }
    __builtin_amdgcn_s_setprio(0);
  }

  // epilogue: store NORMALIZED O (f16-safe), plus (m,l) per q-row
  float invl = 1.0f / l_;
  #pragma unroll
  for (int rg = 0; rg < 16; ++rg) {
    int qr = (rg & 3) + 8 * (rg >> 2) + 4 * hi;
    float iv = __shfl(invl, qr);
    size_t row = (size_t)kq * 16384 + batch * 4096 + q0 + qr;
    #pragma unroll
    for (int dt = 0; dt < 8; ++dt)
      Opart[row * 256 + dt * 32 + ln] = (f16)(O[dt][rg] * iv);
  }
  if (hi == 0) {
    size_t grow = (size_t)kq * 16384 + batch * 4096 + q0 + ln;
    Ml[grow * 2] = m_;
    Ml[grow * 2 + 1] = l_;
  }
#undef STAGE
#undef QKS
#undef PVS
#undef ROWMAX
#undef SM_EXP
#undef P2FRAG
#undef SM_FINISH
}

// ---- Kernel D: split-K merge (m stored in log2 domain -> exp2 weights) ----
__global__ __launch_bounds__(256) void merge_kernel(
    const f16* __restrict__ Opart, const float* __restrict__ Ml,
    float* __restrict__ out) {
  int gid = blockIdx.x * 256 + threadIdx.x;
  int row = gid >> 5, d0 = (gid & 31) * 8;
  float m[4], l[4];
  #pragma unroll
  for (int p = 0; p < 4; ++p) {
    m[p] = Ml[((size_t)p * 16384 + row) * 2];
    l[p] = Ml[((size_t)p * 16384 + row) * 2 + 1];
  }
  float M = fmaxf(fmaxf(m[0], m[1]), fmaxf(m[2], m[3]));
  float wl[4], L = 0.f;
  #pragma unroll
  for (int p = 0; p < 4; ++p) { wl[p] = exp2f(m[p] - M) * l[p]; L += wl[p]; }
  float o[8] = {0.f, 0.f, 0.f, 0.f, 0.f, 0.f, 0.f, 0.f};
  #pragma unroll
  for (int p = 0; p < 4; ++p) {
    f16x8 v = *(const f16x8*)(Opart + ((size_t)p * 16384 + row) * 256 + d0);
    #pragma unroll
    for (int j = 0; j < 8; ++j) o[j] += wl[p] * (float)v[j];
  }
  float invL = 1.0f / L;
  float4 o0 = {o[0] * invL, o[1] * invL, o[2] * invL, o[3] * invL};
  float4 o1 = {o[4] * invL, o[5] * invL, o[6] * invL, o[7] * invL};
  *(float4*)(out + (size_t)row * 256 + d0) = o0;
  *(float4*)(out + (size_t)row * 256 + d0 + 4) = o1;
}

extern "C" void kernel_launch(void* const* d_in, const int* in_sizes, int n_in,
                              void* d_out, int out_size, void* d_ws, size_t ws_size,
                              hipStream_t stream) {
  const float* x  = (const float*)d_in[0];
  const float* Wq = (const float*)d_in[1];
  const float* bq = (const float*)d_in[2];
  const float* Wk = (const float*)d_in[3];
  const float* bk = (const float*)d_in[4];
  const float* Wv = (const float*)d_in[5];
  const float* bv = (const float*)d_in[6];
  float* out = (float*)d_out;

  u16* Wh = (u16*)d_ws;
  u16* Wl = Wh + 3 * 65536;
  f16* Qf = (f16*)(Wl + 3 * 65536);
  f16* Kf = Qf + (size_t)16384 * 256;
  f16* Vt = Kf + (size_t)16384 * 256;
  f16* Opart = Vt + (size_t)4 * 256 * 4096;
  float* Ml = (float*)(Opart + (size_t)4 * 16384 * 256);

  wt_kernel<<<48, 256, 0, stream>>>(Wq, Wk, Wv, Wh, Wl);
  proj_kernel<<<dim3(128, 3), 256, 0, stream>>>(x, bq, bk, bv, Wh, Wl, Qf, Kf, Vt);
  attn_kernel<<<256, 512, 0, stream>>>(Qf, Kf, Vt, Opart, Ml);
  merge_kernel<<<2048, 256, 0, stream>>>(Opart, Ml, out);
}

// Round 12
// 153.941 us; speedup vs baseline: 1.2909x; 1.2661x over previous
//
#include <hip/hip_runtime.h>
#include <stdint.h>

typedef __bf16 bf16;
typedef bf16 bf16x8 __attribute__((ext_vector_type(8)));
typedef _Float16 f16;
typedef f16 f16x8 __attribute__((ext_vector_type(8)));
typedef f16 f16x4 __attribute__((ext_vector_type(4)));
typedef float f32x4 __attribute__((ext_vector_type(4)));
typedef float f32x16 __attribute__((ext_vector_type(16)));
typedef unsigned short u16;
typedef unsigned int u32;
typedef u32 u32x2 __attribute__((ext_vector_type(2)));
typedef u16 u16x8v __attribute__((ext_vector_type(8)));

#define LOG2E 1.44269504088896340736f

__device__ __forceinline__ u16 f2bf(float f) {
  u32 u = __float_as_uint(f);
  u32 r = u + 0x7fffu + ((u >> 16) & 1u);
  return (u16)(r >> 16);
}
__device__ __forceinline__ float bf2f(u16 h) { return __uint_as_float(((u32)h) << 16); }

__device__ __forceinline__ u32 pkrtz(float a, float b) {
  auto r = __builtin_amdgcn_cvt_pkrtz(a, b);   // f16x2: a->[15:0], b->[31:16]
  u32 u; __builtin_memcpy(&u, &r, 4);
  return u;
}
// cross-32 reduce helpers via permlane32_swap (VALU, no LDS pipe)
__device__ __forceinline__ float xmax32(float v) {
  u32x2 r = __builtin_amdgcn_permlane32_swap(__float_as_uint(v), __float_as_uint(v), false, false);
  return fmaxf(__uint_as_float(r[0]), __uint_as_float(r[1]));
}
__device__ __forceinline__ float xsum32(float v) {
  u32x2 r = __builtin_amdgcn_permlane32_swap(__float_as_uint(v), __float_as_uint(v), false, false);
  return __uint_as_float(r[0]) + __uint_as_float(r[1]);
}

union ABu { u16x8v u; bf16x8 b; };
union PAu { u32 w[4]; f16x8 v; };

// ---- Kernel A: Wh/Wl[w][out][in] = split-bf16 of W_w[in][out] ----
__global__ void wt_kernel(const float* __restrict__ Wq, const float* __restrict__ Wk,
                          const float* __restrict__ Wv, u16* __restrict__ Wh,
                          u16* __restrict__ Wl) {
  int w = blockIdx.x >> 4;
  int chunk = blockIdx.x & 15;
  const float* W = (w == 0) ? Wq : (w == 1) ? Wk : Wv;
  int t = threadIdx.x;
  int o = chunk * 16 + (t & 15);
  int i0 = (t >> 4) * 16;
  u16x8v h0, h1, l0, l1;
  #pragma unroll
  for (int ii = 0; ii < 8; ++ii) {
    float v0 = W[(size_t)(i0 + ii) * 256 + o];
    u16 h = f2bf(v0); h0[ii] = h; l0[ii] = f2bf(v0 - bf2f(h));
    float v1 = W[(size_t)(i0 + 8 + ii) * 256 + o];
    h = f2bf(v1); h1[ii] = h; l1[ii] = f2bf(v1 - bf2f(h));
  }
  size_t base = (size_t)w * 65536 + (size_t)o * 256 + i0;
  *(u16x8v*)(Wh + base) = h0; *(u16x8v*)(Wh + base + 8) = h1;
  *(u16x8v*)(Wl + base) = l0; *(u16x8v*)(Wl + base + 8) = l1;
}

// ---- Kernel B: QKV projection (fp32-exact 3-pass bf16), W slices staged in LDS ----
// Q output is pre-scaled by log2(e) so attention softmax runs in exp2 domain.
__global__ __launch_bounds__(256, 2) void proj_kernel(
    const float* __restrict__ x, const float* __restrict__ bq,
    const float* __restrict__ bk, const float* __restrict__ bv,
    const u16* __restrict__ Wh, const u16* __restrict__ Wl,
    f16* __restrict__ Qf, f16* __restrict__ Kf, f16* __restrict__ Vt) {
  __shared__ __align__(16) char Whs[16384];   // [256 out-rows][32 in] bf16, swizzled
  __shared__ __align__(16) char Wls[16384];

  int m = blockIdx.x, w = blockIdx.y;
  int tid = threadIdx.x, lane = tid & 63, wv = tid >> 6;
  int r = lane & 15, c = lane >> 4;
  int row0 = m * 128 + wv * 32;
  const char* Whw = (const char*)(Wh + (size_t)w * 65536);
  const char* Wlw = (const char*)(Wl + (size_t)w * 65536);
  const float* bias = (w == 0) ? bq : (w == 1) ? bk : bv;

  f32x4 acc[2][16];
  #pragma unroll
  for (int g = 0; g < 2; ++g)
    #pragma unroll
    for (int n = 0; n < 16; ++n) acc[g][n] = (f32x4)0.0f;

  for (int ks = 0; ks < 8; ++ks) {
    if (ks) __syncthreads();
    #pragma unroll
    for (int ss = 0; ss < 4; ++ss) {
      int slot = ss * 256 + tid;
      int row = slot >> 2, c4 = slot & 3;
      int dby = (c4 << 4) ^ (((row >> 1) & 3) << 4);
      const char* gh = Whw + (size_t)row * 512 + ks * 64 + dby;
      const char* gl = Wlw + (size_t)row * 512 + ks * 64 + dby;
      __builtin_amdgcn_global_load_lds(
          (const __attribute__((address_space(1))) void*)gh,
          (__attribute__((address_space(3))) void*)(Whs + slot * 16), 16, 0, 0);
      __builtin_amdgcn_global_load_lds(
          (const __attribute__((address_space(1))) void*)gl,
          (__attribute__((address_space(3))) void*)(Wls + slot * 16), 16, 0, 0);
    }
    __syncthreads();

    ABu ah[2], al[2];
    #pragma unroll
    for (int g = 0; g < 2; ++g) {
      const float* xrow = x + (size_t)(row0 + g * 16 + r) * 256 + ks * 32 + c * 8;
      float4 a0 = *(const float4*)(xrow);
      float4 a1 = *(const float4*)(xrow + 4);
      float xv[8] = {a0.x, a0.y, a0.z, a0.w, a1.x, a1.y, a1.z, a1.w};
      #pragma unroll
      for (int j = 0; j < 8; ++j) {
        u16 h = f2bf(xv[j]);
        ah[g].u[j] = h;
        al[g].u[j] = f2bf(xv[j] - bf2f(h));
      }
    }
    #pragma unroll
    for (int n = 0; n < 16; ++n) {
      int wrow = n * 16 + r;
      int wof = (c * 16) ^ (((wrow >> 1) & 3) << 4);
      bf16x8 whf = *(const bf16x8*)(Whs + wrow * 64 + wof);
      bf16x8 wlf = *(const bf16x8*)(Wls + wrow * 64 + wof);
      #pragma unroll
      for (int g = 0; g < 2; ++g) {
        acc[g][n] = __builtin_amdgcn_mfma_f32_16x16x32_bf16(ah[g].b, whf, acc[g][n], 0, 0, 0);
        acc[g][n] = __builtin_amdgcn_mfma_f32_16x16x32_bf16(al[g].b, whf, acc[g][n], 0, 0, 0);
        acc[g][n] = __builtin_amdgcn_mfma_f32_16x16x32_bf16(ah[g].b, wlf, acc[g][n], 0, 0, 0);
      }
    }
  }

  if (w < 2) {
    f16* outp = (w == 0) ? Qf : Kf;
    float osc = (w == 0) ? LOG2E : 1.0f;   // exp2-domain scores
    #pragma unroll
    for (int g = 0; g < 2; ++g)
      #pragma unroll
      for (int n = 0; n < 16; ++n) {
        int col = n * 16 + r;
        float bb = bias[col];
        #pragma unroll
        for (int i = 0; i < 4; ++i) {
          float v = fmaxf(acc[g][n][i] + bb, 0.0f) * osc;
          outp[(size_t)(row0 + g * 16 + c * 4 + i) * 256 + col] = (f16)v;
        }
      }
  } else {
    #pragma unroll
    for (int g = 0; g < 2; ++g) {
      int grow = row0 + g * 16 + c * 4;
      int b = grow >> 12, s0 = grow & 4095;
      #pragma unroll
      for (int n = 0; n < 16; ++n) {
        int d = n * 16 + r;
        float bb = bias[d];
        f16x4 pk;
        #pragma unroll
        for (int i = 0; i < 4; ++i) pk[i] = (f16)(acc[g][n][i] + bb);
        *(f16x4*)(Vt + (size_t)(b * 256 + d) * 4096 + s0) = pk;
      }
    }
  }
}

// ---- Kernel C: flash attention ----
// 256 blocks x 8 waves, 32 q-rows/wave, KVBLK=64, splitK=4, K/V dbuf (128KB LDS).
// Wave-parity phase stagger: even waves process key-half A=[0,32) first, odd
// waves half B=[32,64) first. Best measured structure (r7: 124 us).
__global__ __launch_bounds__(512, 2) void attn_kernel(
    const f16* __restrict__ Qf, const f16* __restrict__ Kf,
    const f16* __restrict__ Vt, f16* __restrict__ Opart, float* __restrict__ Ml) {
  __shared__ __align__(16) char Ksm[2][32768];   // [64 keys][256 d] f16, swizzled
  __shared__ __align__(16) char Vsm[2][32768];   // [256 d][64 keys] f16, swizzled

  int bid = blockIdx.x;
  int xcd = bid & 7;
  int batch = xcd >> 1;
  int kq = ((xcd & 1) << 1) | ((bid >> 3) & 1);
  int qtl = bid >> 4;
  int tid = threadIdx.x, lane = tid & 63, wv = tid >> 6;
  int ln = lane & 31, hi = lane >> 5;
  int q0 = qtl * 256 + wv * 32;
  int kv0 = kq * 1024;
  int par = wv & 1;

  f16x8 qf[16];
  {
    const f16* qp = Qf + ((size_t)(batch * 4096 + q0 + ln)) * 256 + hi * 8;
    #pragma unroll
    for (int ks = 0; ks < 16; ++ks) qf[ks] = *(const f16x8*)(qp + ks * 16);
  }

  f32x16 O[8];
  #pragma unroll
  for (int dt = 0; dt < 8; ++dt) O[dt] = (f32x16)0.0f;
  float m_ = -1.0e30f, l_ = 0.0f;

  const char* Kbase = (const char*)(Kf + ((size_t)(batch * 4096 + kv0)) * 256);
  const char* Vbase = (const char*)(Vt + (size_t)batch * 1048576 + kv0);

#define STAGE(T, BF)                                                           \
  {                                                                            \
    _Pragma("unroll")                                                          \
    for (int rr = 0; rr < 4; ++rr) {                                           \
      int slot = rr * 512 + tid;                                               \
      int krow = slot >> 5;                                                    \
      int dby = ((slot & 31) << 4) ^ ((krow & 7) << 4);                        \
      const char* g = Kbase + (size_t)((T) * 64 + krow) * 512 + dby;           \
      __builtin_amdgcn_global_load_lds(                                        \
          (const __attribute__((address_space(1))) void*)g,                    \
          (__attribute__((address_space(3))) void*)(Ksm[BF] + slot * 16), 16, 0, 0); \
    }                                                                          \
    _Pragma("unroll")                                                          \
    for (int rr = 0; rr < 4; ++rr) {                                           \
      int slot = rr * 512 + tid;                                               \
      int vrow = slot >> 3;                                                    \
      int dby = ((slot & 7) << 4) ^ ((vrow & 7) << 4);                         \
      const char* g = Vbase + (size_t)vrow * 8192 + (T) * 128 + dby;           \
      __builtin_amdgcn_global_load_lds(                                        \
          (const __attribute__((address_space(1))) void*)g,                    \
          (__attribute__((address_space(3))) void*)(Vsm[BF] + slot * 16), 16, 0, 0); \
    }                                                                          \
  }

  int kswz = (ln & 7) << 4;
  int vswz = (ln & 7) << 4;
  int hi16 = hi * 16;
  int kbA = par * 32;          // even waves: keys [0,32) first; odd: [32,64)
  int kbB = 32 - kbA;

  // exp2-domain softmax (scores pre-scaled by log2e via Q)
#define SOFTMAX(SA, PA0, PA1)                                                  \
  {                                                                            \
    float pm = fmaxf(                                                          \
        fmaxf(fmaxf(fmaxf(SA[0], SA[1]), fmaxf(SA[2], SA[3])),                 \
              fmaxf(fmaxf(SA[4], SA[5]), fmaxf(SA[6], SA[7]))),                \
        fmaxf(fmaxf(fmaxf(SA[8], SA[9]), fmaxf(SA[10], SA[11])),               \
              fmaxf(fmaxf(SA[12], SA[13]), fmaxf(SA[14], SA[15]))));           \
    pm = xmax32(pm);                                                           \
    if (!__all(pm <= m_ + 11.5416f)) {    /* defer-max, THR=8 in e-domain */   \
      float mn = fmaxf(m_, pm);                                                \
      float sc = exp2f(m_ - mn);                                               \
      m_ = mn; l_ *= sc;                                                       \
      _Pragma("unroll")                                                        \
      for (int rg = 0; rg < 16; ++rg) {                                        \
        float srg = __shfl(sc, (rg & 3) + 8 * (rg >> 2) + 4 * hi);             \
        _Pragma("unroll")                                                      \
        for (int dt = 0; dt < 8; ++dt) O[dt][rg] *= srg;                       \
      }                                                                        \
    }                                                                          \
    float p_[16];                                                              \
    _Pragma("unroll")                                                          \
    for (int j = 0; j < 16; ++j) p_[j] = exp2f(SA[j] - m_);                    \
    float ps = (((p_[0] + p_[1]) + (p_[2] + p_[3])) +                          \
                ((p_[4] + p_[5]) + (p_[6] + p_[7]))) +                         \
               (((p_[8] + p_[9]) + (p_[10] + p_[11])) +                        \
                ((p_[12] + p_[13]) + (p_[14] + p_[15])));                      \
    l_ += xsum32(ps);                                                          \
    {                                                                          \
      u32x2 r1 = __builtin_amdgcn_permlane32_swap(pkrtz(p_[0], p_[1]), pkrtz(p_[4], p_[5]), false, false); \
      u32x2 r2 = __builtin_amdgcn_permlane32_swap(pkrtz(p_[2], p_[3]), pkrtz(p_[6], p_[7]), false, false); \
      PA0.w[0] = r1[0]; PA0.w[1] = r2[0]; PA0.w[2] = r1[1]; PA0.w[3] = r2[1];  \
      u32x2 r3 = __builtin_amdgcn_permlane32_swap(pkrtz(p_[8], p_[9]), pkrtz(p_[12], p_[13]), false, false); \
      u32x2 r4 = __builtin_amdgcn_permlane32_swap(pkrtz(p_[10], p_[11]), pkrtz(p_[14], p_[15]), false, false); \
      PA1.w[0] = r3[0]; PA1.w[1] = r4[0]; PA1.w[2] = r3[1]; PA1.w[3] = r4[1];  \
    }                                                                          \
  }

  STAGE(0, 0);

  for (int t = 0; t < 16; ++t) {
    __builtin_amdgcn_s_barrier();
    if (t < 15) {
      STAGE(t + 1, (t + 1) & 1);
      asm volatile("s_waitcnt vmcnt(8)" ::: "memory");
    } else {
      asm volatile("s_waitcnt vmcnt(0)" ::: "memory");
    }
    __builtin_amdgcn_sched_barrier(0);
    __builtin_amdgcn_s_barrier();

    const char* Kc = Ksm[t & 1];
    const char* Vc = Vsm[t & 1];
    const char* KcA = Kc + kbA * 512;
    const char* KcB = Kc + kbB * 512;
    int vbA = kbA * 2, vbB = kbB * 2;   // byte offset within 128B V row

    // ---- phase 1: QK(half A) ----
    f32x16 sA = (f32x16)0.0f;
    __builtin_amdgcn_s_setprio(1);
    #pragma unroll
    for (int ks = 0; ks < 16; ++ks) {
      f16x8 kf = *(const f16x8*)(KcA + ln * 512 + ((ks * 32 + hi16) ^ kswz));
      sA = __builtin_amdgcn_mfma_f32_32x32x16_f16(kf, qf[ks], sA, 0, 0, 0);
    }
    __builtin_amdgcn_s_setprio(0);
    PAu paA0, paA1;
    SOFTMAX(sA, paA0, paA1);

    // ---- phase 2: QK(half B) || PV(half A) ----
    f32x16 sB = (f32x16)0.0f;
    __builtin_amdgcn_s_setprio(1);
    #pragma unroll
    for (int ks = 0; ks < 16; ++ks) {
      f16x8 kf = *(const f16x8*)(KcB + ln * 512 + ((ks * 32 + hi16) ^ kswz));
      sB = __builtin_amdgcn_mfma_f32_32x32x16_f16(kf, qf[ks], sB, 0, 0, 0);
      int dt = ks >> 1, k2 = ks & 1;
      f16x8 vf = *(const f16x8*)(Vc + (dt * 32 + ln) * 128 + ((vbA + k2 * 32 + hi16) ^ vswz));
      O[dt] = __builtin_amdgcn_mfma_f32_32x32x16_f16(k2 ? paA1.v : paA0.v, vf, O[dt], 0, 0, 0);
    }
    __builtin_amdgcn_s_setprio(0);
    PAu paB0, paB1;
    SOFTMAX(sB, paB0, paB1);

    // ---- phase 3: PV(half B) ----
    __builtin_amdgcn_s_setprio(1);
    #pragma unroll
    for (int ks = 0; ks < 16; ++ks) {
      int dt = ks >> 1, k2 = ks & 1;
      f16x8 vf = *(const f16x8*)(Vc + (dt * 32 + ln) * 128 + ((vbB + k2 * 32 + hi16) ^ vswz));
      O[dt] = __builtin_amdgcn_mfma_f32_32x32x16_f16(k2 ? paB1.v : paB0.v, vf, O[dt], 0, 0, 0);
    }
    __builtin_amdgcn_s_setprio(0);
  }

  // epilogue: store NORMALIZED O (f16-safe), plus (m,l) per q-row
  float invl = 1.0f / l_;
  #pragma unroll
  for (int rg = 0; rg < 16; ++rg) {
    int qr = (rg & 3) + 8 * (rg >> 2) + 4 * hi;
    float iv = __shfl(invl, qr);
    size_t row = (size_t)kq * 16384 + batch * 4096 + q0 + qr;
    #pragma unroll
    for (int dt = 0; dt < 8; ++dt)
      Opart[row * 256 + dt * 32 + ln] = (f16)(O[dt][rg] * iv);
  }
  if (hi == 0) {
    size_t grow = (size_t)kq * 16384 + batch * 4096 + q0 + ln;
    Ml[grow * 2] = m_;
    Ml[grow * 2 + 1] = l_;
  }
#undef STAGE
#undef SOFTMAX
}

// ---- Kernel D: split-K merge (m stored in log2 domain -> exp2 weights) ----
__global__ __launch_bounds__(256) void merge_kernel(
    const f16* __restrict__ Opart, const float* __restrict__ Ml,
    float* __restrict__ out) {
  int gid = blockIdx.x * 256 + threadIdx.x;
  int row = gid >> 5, d0 = (gid & 31) * 8;
  float m[4], l[4];
  #pragma unroll
  for (int p = 0; p < 4; ++p) {
    m[p] = Ml[((size_t)p * 16384 + row) * 2];
    l[p] = Ml[((size_t)p * 16384 + row) * 2 + 1];
  }
  float M = fmaxf(fmaxf(m[0], m[1]), fmaxf(m[2], m[3]));
  float wl[4], L = 0.f;
  #pragma unroll
  for (int p = 0; p < 4; ++p) { wl[p] = exp2f(m[p] - M) * l[p]; L += wl[p]; }
  float o[8] = {0.f, 0.f, 0.f, 0.f, 0.f, 0.f, 0.f, 0.f};
  #pragma unroll
  for (int p = 0; p < 4; ++p) {
    f16x8 v = *(const f16x8*)(Opart + ((size_t)p * 16384 + row) * 256 + d0);
    #pragma unroll
    for (int j = 0; j < 8; ++j) o[j] += wl[p] * (float)v[j];
  }
  float invL = 1.0f / L;
  float4 o0 = {o[0] * invL, o[1] * invL, o[2] * invL, o[3] * invL};
  float4 o1 = {o[4] * invL, o[5] * invL, o[6] * invL, o[7] * invL};
  *(float4*)(out + (size_t)row * 256 + d0) = o0;
  *(float4*)(out + (size_t)row * 256 + d0 + 4) = o1;
}

extern "C" void kernel_launch(void* const* d_in, const int* in_sizes, int n_in,
                              void* d_out, int out_size, void* d_ws, size_t ws_size,
                              hipStream_t stream) {
  const float* x  = (const float*)d_in[0];
  const float* Wq = (const float*)d_in[1];
  const float* bq = (const float*)d_in[2];
  const float* Wk = (const float*)d_in[3];
  const float* bk = (const float*)d_in[4];
  const float* Wv = (const float*)d_in[5];
  const float* bv = (const float*)d_in[6];
  float* out = (float*)d_out;

  u16* Wh = (u16*)d_ws;
  u16* Wl = Wh + 3 * 65536;
  f16* Qf = (f16*)(Wl + 3 * 65536);
  f16* Kf = Qf + (size_t)16384 * 256;
  f16* Vt = Kf + (size_t)16384 * 256;
  f16* Opart = Vt + (size_t)4 * 256 * 4096;
  float* Ml = (float*)(Opart + (size_t)4 * 16384 * 256);

  wt_kernel<<<48, 256, 0, stream>>>(Wq, Wk, Wv, Wh, Wl);
  proj_kernel<<<dim3(128, 3), 256, 0, stream>>>(x, bq, bk, bv, Wh, Wl, Qf, Kf, Vt);
  attn_kernel<<<256, 512, 0, stream>>>(Qf, Kf, Vt, Opart, Ml);
  merge_kernel<<<2048, 256, 0, stream>>>(Opart, Ml, out);
}

// Round 13
// 150.933 us; speedup vs baseline: 1.3166x; 1.0199x over previous
//
#include <hip/hip_runtime.h>
#include <stdint.h>

typedef __bf16 bf16;
typedef bf16 bf16x8 __attribute__((ext_vector_type(8)));
typedef _Float16 f16;
typedef f16 f16x8 __attribute__((ext_vector_type(8)));
typedef f16 f16x4 __attribute__((ext_vector_type(4)));
typedef float f32x4 __attribute__((ext_vector_type(4)));
typedef float f32x16 __attribute__((ext_vector_type(16)));
typedef unsigned short u16;
typedef unsigned int u32;
typedef u32 u32x2 __attribute__((ext_vector_type(2)));
typedef u16 u16x8v __attribute__((ext_vector_type(8)));

#define LOG2E 1.44269504088896340736f

__device__ __forceinline__ u16 f2bf(float f) {
  u32 u = __float_as_uint(f);
  u32 r = u + 0x7fffu + ((u >> 16) & 1u);
  return (u16)(r >> 16);
}
__device__ __forceinline__ float bf2f(u16 h) { return __uint_as_float(((u32)h) << 16); }

__device__ __forceinline__ u32 pkrtz(float a, float b) {
  auto r = __builtin_amdgcn_cvt_pkrtz(a, b);   // f16x2: a->[15:0], b->[31:16]
  u32 u; __builtin_memcpy(&u, &r, 4);
  return u;
}
// cross-32 reduce helpers via permlane32_swap (VALU, no LDS pipe)
__device__ __forceinline__ float xmax32(float v) {
  u32x2 r = __builtin_amdgcn_permlane32_swap(__float_as_uint(v), __float_as_uint(v), false, false);
  return fmaxf(__uint_as_float(r[0]), __uint_as_float(r[1]));
}
__device__ __forceinline__ float xsum32(float v) {
  u32x2 r = __builtin_amdgcn_permlane32_swap(__float_as_uint(v), __float_as_uint(v), false, false);
  return __uint_as_float(r[0]) + __uint_as_float(r[1]);
}

union ABu { u16x8v u; bf16x8 b; };
union PAu { u32 w[4]; f16x8 v; };

// ---- Kernel A: Wh/Wl[w][out][in] = split-bf16 of W_w[in][out] ----
__global__ void wt_kernel(const float* __restrict__ Wq, const float* __restrict__ Wk,
                          const float* __restrict__ Wv, u16* __restrict__ Wh,
                          u16* __restrict__ Wl) {
  int w = blockIdx.x >> 4;
  int chunk = blockIdx.x & 15;
  const float* W = (w == 0) ? Wq : (w == 1) ? Wk : Wv;
  int t = threadIdx.x;
  int o = chunk * 16 + (t & 15);
  int i0 = (t >> 4) * 16;
  u16x8v h0, h1, l0, l1;
  #pragma unroll
  for (int ii = 0; ii < 8; ++ii) {
    float v0 = W[(size_t)(i0 + ii) * 256 + o];
    u16 h = f2bf(v0); h0[ii] = h; l0[ii] = f2bf(v0 - bf2f(h));
    float v1 = W[(size_t)(i0 + 8 + ii) * 256 + o];
    h = f2bf(v1); h1[ii] = h; l1[ii] = f2bf(v1 - bf2f(h));
  }
  size_t base = (size_t)w * 65536 + (size_t)o * 256 + i0;
  *(u16x8v*)(Wh + base) = h0; *(u16x8v*)(Wh + base + 8) = h1;
  *(u16x8v*)(Wl + base) = l0; *(u16x8v*)(Wl + base + 8) = l1;
}

// ---- Kernel B: QKV projection (fp32-exact 3-pass bf16), W slices staged in LDS ----
// Q output is pre-scaled by log2(e) so attention softmax runs in exp2 domain.
__global__ __launch_bounds__(256, 2) void proj_kernel(
    const float* __restrict__ x, const float* __restrict__ bq,
    const float* __restrict__ bk, const float* __restrict__ bv,
    const u16* __restrict__ Wh, const u16* __restrict__ Wl,
    f16* __restrict__ Qf, f16* __restrict__ Kf, f16* __restrict__ Vt) {
  __shared__ __align__(16) char Whs[16384];   // [256 out-rows][32 in] bf16, swizzled
  __shared__ __align__(16) char Wls[16384];

  int m = blockIdx.x, w = blockIdx.y;
  int tid = threadIdx.x, lane = tid & 63, wv = tid >> 6;
  int r = lane & 15, c = lane >> 4;
  int row0 = m * 128 + wv * 32;
  const char* Whw = (const char*)(Wh + (size_t)w * 65536);
  const char* Wlw = (const char*)(Wl + (size_t)w * 65536);
  const float* bias = (w == 0) ? bq : (w == 1) ? bk : bv;

  f32x4 acc[2][16];
  #pragma unroll
  for (int g = 0; g < 2; ++g)
    #pragma unroll
    for (int n = 0; n < 16; ++n) acc[g][n] = (f32x4)0.0f;

  for (int ks = 0; ks < 8; ++ks) {
    if (ks) __syncthreads();
    #pragma unroll
    for (int ss = 0; ss < 4; ++ss) {
      int slot = ss * 256 + tid;
      int row = slot >> 2, c4 = slot & 3;
      int dby = (c4 << 4) ^ (((row >> 1) & 3) << 4);
      const char* gh = Whw + (size_t)row * 512 + ks * 64 + dby;
      const char* gl = Wlw + (size_t)row * 512 + ks * 64 + dby;
      __builtin_amdgcn_global_load_lds(
          (const __attribute__((address_space(1))) void*)gh,
          (__attribute__((address_space(3))) void*)(Whs + slot * 16), 16, 0, 0);
      __builtin_amdgcn_global_load_lds(
          (const __attribute__((address_space(1))) void*)gl,
          (__attribute__((address_space(3))) void*)(Wls + slot * 16), 16, 0, 0);
    }
    __syncthreads();

    ABu ah[2], al[2];
    #pragma unroll
    for (int g = 0; g < 2; ++g) {
      const float* xrow = x + (size_t)(row0 + g * 16 + r) * 256 + ks * 32 + c * 8;
      float4 a0 = *(const float4*)(xrow);
      float4 a1 = *(const float4*)(xrow + 4);
      float xv[8] = {a0.x, a0.y, a0.z, a0.w, a1.x, a1.y, a1.z, a1.w};
      #pragma unroll
      for (int j = 0; j < 8; ++j) {
        u16 h = f2bf(xv[j]);
        ah[g].u[j] = h;
        al[g].u[j] = f2bf(xv[j] - bf2f(h));
      }
    }
    #pragma unroll
    for (int n = 0; n < 16; ++n) {
      int wrow = n * 16 + r;
      int wof = (c * 16) ^ (((wrow >> 1) & 3) << 4);
      bf16x8 whf = *(const bf16x8*)(Whs + wrow * 64 + wof);
      bf16x8 wlf = *(const bf16x8*)(Wls + wrow * 64 + wof);
      #pragma unroll
      for (int g = 0; g < 2; ++g) {
        acc[g][n] = __builtin_amdgcn_mfma_f32_16x16x32_bf16(ah[g].b, whf, acc[g][n], 0, 0, 0);
        acc[g][n] = __builtin_amdgcn_mfma_f32_16x16x32_bf16(al[g].b, whf, acc[g][n], 0, 0, 0);
        acc[g][n] = __builtin_amdgcn_mfma_f32_16x16x32_bf16(ah[g].b, wlf, acc[g][n], 0, 0, 0);
      }
    }
  }

  if (w < 2) {
    f16* outp = (w == 0) ? Qf : Kf;
    float osc = (w == 0) ? LOG2E : 1.0f;   // exp2-domain scores
    #pragma unroll
    for (int g = 0; g < 2; ++g)
      #pragma unroll
      for (int n = 0; n < 16; ++n) {
        int col = n * 16 + r;
        float bb = bias[col];
        #pragma unroll
        for (int i = 0; i < 4; ++i) {
          float v = fmaxf(acc[g][n][i] + bb, 0.0f) * osc;
          outp[(size_t)(row0 + g * 16 + c * 4 + i) * 256 + col] = (f16)v;
        }
      }
  } else {
    #pragma unroll
    for (int g = 0; g < 2; ++g) {
      int grow = row0 + g * 16 + c * 4;
      int b = grow >> 12, s0 = grow & 4095;
      #pragma unroll
      for (int n = 0; n < 16; ++n) {
        int d = n * 16 + r;
        float bb = bias[d];
        f16x4 pk;
        #pragma unroll
        for (int i = 0; i < 4; ++i) pk[i] = (f16)(acc[g][n][i] + bb);
        *(f16x4*)(Vt + (size_t)(b * 256 + d) * 4096 + s0) = pk;
      }
    }
  }
}

// ---- Kernel C: flash attention ----
// 256 blocks x 8 waves, 32 q-rows/wave, KVBLK=64, splitK=4, K/V dbuf (128KB LDS).
// ONE barrier + ONE (free) vmcnt(0) per round: stage(t) was issued a full round
// earlier, so draining it at round-top is free; the single barrier then both
// publishes stage(t) (each wave drained before entering) and proves all waves
// finished compute(t-1) (so overwriting buf[(t+1)&1] is safe).
__global__ __launch_bounds__(512, 2) void attn_kernel(
    const f16* __restrict__ Qf, const f16* __restrict__ Kf,
    const f16* __restrict__ Vt, f16* __restrict__ Opart, float* __restrict__ Ml) {
  __shared__ __align__(16) char Ksm[2][32768];   // [64 keys][256 d] f16, swizzled
  __shared__ __align__(16) char Vsm[2][32768];   // [256 d][64 keys] f16, swizzled

  int bid = blockIdx.x;
  int xcd = bid & 7;
  int batch = xcd >> 1;
  int kq = ((xcd & 1) << 1) | ((bid >> 3) & 1);
  int qtl = bid >> 4;
  int tid = threadIdx.x, lane = tid & 63, wv = tid >> 6;
  int ln = lane & 31, hi = lane >> 5;
  int q0 = qtl * 256 + wv * 32;
  int kv0 = kq * 1024;
  int par = wv & 1;

  f16x8 qf[16];
  {
    const f16* qp = Qf + ((size_t)(batch * 4096 + q0 + ln)) * 256 + hi * 8;
    #pragma unroll
    for (int ks = 0; ks < 16; ++ks) qf[ks] = *(const f16x8*)(qp + ks * 16);
  }

  f32x16 O[8];
  #pragma unroll
  for (int dt = 0; dt < 8; ++dt) O[dt] = (f32x16)0.0f;
  float m_ = -1.0e30f, l_ = 0.0f;

  const char* Kbase = (const char*)(Kf + ((size_t)(batch * 4096 + kv0)) * 256);
  const char* Vbase = (const char*)(Vt + (size_t)batch * 1048576 + kv0);

#define STAGE(T, BF)                                                           \
  {                                                                            \
    _Pragma("unroll")                                                          \
    for (int rr = 0; rr < 4; ++rr) {                                           \
      int slot = rr * 512 + tid;                                               \
      int krow = slot >> 5;                                                    \
      int dby = ((slot & 31) << 4) ^ ((krow & 7) << 4);                        \
      const char* g = Kbase + (size_t)((T) * 64 + krow) * 512 + dby;           \
      __builtin_amdgcn_global_load_lds(                                        \
          (const __attribute__((address_space(1))) void*)g,                    \
          (__attribute__((address_space(3))) void*)(Ksm[BF] + slot * 16), 16, 0, 0); \
    }                                                                          \
    _Pragma("unroll")                                                          \
    for (int rr = 0; rr < 4; ++rr) {                                           \
      int slot = rr * 512 + tid;                                               \
      int vrow = slot >> 3;                                                    \
      int dby = ((slot & 7) << 4) ^ ((vrow & 7) << 4);                         \
      const char* g = Vbase + (size_t)vrow * 8192 + (T) * 128 + dby;           \
      __builtin_amdgcn_global_load_lds(                                        \
          (const __attribute__((address_space(1))) void*)g,                    \
          (__attribute__((address_space(3))) void*)(Vsm[BF] + slot * 16), 16, 0, 0); \
    }                                                                          \
  }

  int kswz = (ln & 7) << 4;
  int vswz = (ln & 7) << 4;
  int hi16 = hi * 16;
  int kbA = par * 32;          // even waves: keys [0,32) first; odd: [32,64)
  int kbB = 32 - kbA;

  // exp2-domain softmax (scores pre-scaled by log2e via Q)
#define SOFTMAX(SA, PA0, PA1)                                                  \
  {                                                                            \
    float pm = fmaxf(                                                          \
        fmaxf(fmaxf(fmaxf(SA[0], SA[1]), fmaxf(SA[2], SA[3])),                 \
              fmaxf(fmaxf(SA[4], SA[5]), fmaxf(SA[6], SA[7]))),                \
        fmaxf(fmaxf(fmaxf(SA[8], SA[9]), fmaxf(SA[10], SA[11])),               \
              fmaxf(fmaxf(SA[12], SA[13]), fmaxf(SA[14], SA[15]))));           \
    pm = xmax32(pm);                                                           \
    if (!__all(pm <= m_ + 11.5416f)) {    /* defer-max, THR=8 in e-domain */   \
      float mn = fmaxf(m_, pm);                                                \
      float sc = exp2f(m_ - mn);                                               \
      m_ = mn; l_ *= sc;                                                       \
      _Pragma("unroll")                                                        \
      for (int rg = 0; rg < 16; ++rg) {                                        \
        float srg = __shfl(sc, (rg & 3) + 8 * (rg >> 2) + 4 * hi);             \
        _Pragma("unroll")                                                      \
        for (int dt = 0; dt < 8; ++dt) O[dt][rg] *= srg;                       \
      }                                                                        \
    }                                                                          \
    float p_[16];                                                              \
    _Pragma("unroll")                                                          \
    for (int j = 0; j < 16; ++j) p_[j] = exp2f(SA[j] - m_);                    \
    float ps = (((p_[0] + p_[1]) + (p_[2] + p_[3])) +                          \
                ((p_[4] + p_[5]) + (p_[6] + p_[7]))) +                         \
               (((p_[8] + p_[9]) + (p_[10] + p_[11])) +                        \
                ((p_[12] + p_[13]) + (p_[14] + p_[15])));                      \
    l_ += xsum32(ps);                                                          \
    {                                                                          \
      u32x2 r1 = __builtin_amdgcn_permlane32_swap(pkrtz(p_[0], p_[1]), pkrtz(p_[4], p_[5]), false, false); \
      u32x2 r2 = __builtin_amdgcn_permlane32_swap(pkrtz(p_[2], p_[3]), pkrtz(p_[6], p_[7]), false, false); \
      PA0.w[0] = r1[0]; PA0.w[1] = r2[0]; PA0.w[2] = r1[1]; PA0.w[3] = r2[1];  \
      u32x2 r3 = __builtin_amdgcn_permlane32_swap(pkrtz(p_[8], p_[9]), pkrtz(p_[12], p_[13]), false, false); \
      u32x2 r4 = __builtin_amdgcn_permlane32_swap(pkrtz(p_[10], p_[11]), pkrtz(p_[14], p_[15]), false, false); \
      PA1.w[0] = r3[0]; PA1.w[1] = r4[0]; PA1.w[2] = r3[1]; PA1.w[3] = r4[1];  \
    }                                                                          \
  }

  STAGE(0, 0);

  for (int t = 0; t < 16; ++t) {
    // single sync point per round: my stage(t) drained, then block-wide barrier
    // (publishes everyone's stage(t); proves compute(t-1) done everywhere).
    asm volatile("s_waitcnt vmcnt(0)" ::: "memory");
    __builtin_amdgcn_s_barrier();
    __builtin_amdgcn_sched_barrier(0);       // pin ds_reads below the barrier
    if (t < 15) STAGE(t + 1, (t + 1) & 1);   // overwrites buf last read in t-1

    const char* Kc = Ksm[t & 1];
    const char* Vc = Vsm[t & 1];
    const char* KcA = Kc + kbA * 512;
    const char* KcB = Kc + kbB * 512;
    int vbA = kbA * 2, vbB = kbB * 2;   // byte offset within 128B V row

    // ---- phase 1: QK(half A) ----
    f32x16 sA = (f32x16)0.0f;
    __builtin_amdgcn_s_setprio(1);
    #pragma unroll
    for (int ks = 0; ks < 16; ++ks) {
      f16x8 kf = *(const f16x8*)(KcA + ln * 512 + ((ks * 32 + hi16) ^ kswz));
      sA = __builtin_amdgcn_mfma_f32_32x32x16_f16(kf, qf[ks], sA, 0, 0, 0);
    }
    __builtin_amdgcn_s_setprio(0);
    PAu paA0, paA1;
    SOFTMAX(sA, paA0, paA1);

    // ---- phase 2: QK(half B) || PV(half A) ----
    f32x16 sB = (f32x16)0.0f;
    __builtin_amdgcn_s_setprio(1);
    #pragma unroll
    for (int ks = 0; ks < 16; ++ks) {
      f16x8 kf = *(const f16x8*)(KcB + ln * 512 + ((ks * 32 + hi16) ^ kswz));
      sB = __builtin_amdgcn_mfma_f32_32x32x16_f16(kf, qf[ks], sB, 0, 0, 0);
      int dt = ks >> 1, k2 = ks & 1;
      f16x8 vf = *(const f16x8*)(Vc + (dt * 32 + ln) * 128 + ((vbA + k2 * 32 + hi16) ^ vswz));
      O[dt] = __builtin_amdgcn_mfma_f32_32x32x16_f16(k2 ? paA1.v : paA0.v, vf, O[dt], 0, 0, 0);
    }
    __builtin_amdgcn_s_setprio(0);
    PAu paB0, paB1;
    SOFTMAX(sB, paB0, paB1);

    // ---- phase 3: PV(half B) ----
    __builtin_amdgcn_s_setprio(1);
    #pragma unroll
    for (int ks = 0; ks < 16; ++ks) {
      int dt = ks >> 1, k2 = ks & 1;
      f16x8 vf = *(const f16x8*)(Vc + (dt * 32 + ln) * 128 + ((vbB + k2 * 32 + hi16) ^ vswz));
      O[dt] = __builtin_amdgcn_mfma_f32_32x32x16_f16(k2 ? paB1.v : paB0.v, vf, O[dt], 0, 0, 0);
    }
    __builtin_amdgcn_s_setprio(0);
  }

  // epilogue: store NORMALIZED O (f16-safe), plus (m,l) per q-row
  float invl = 1.0f / l_;
  #pragma unroll
  for (int rg = 0; rg < 16; ++rg) {
    int qr = (rg & 3) + 8 * (rg >> 2) + 4 * hi;
    float iv = __shfl(invl, qr);
    size_t row = (size_t)kq * 16384 + batch * 4096 + q0 + qr;
    #pragma unroll
    for (int dt = 0; dt < 8; ++dt)
      Opart[row * 256 + dt * 32 + ln] = (f16)(O[dt][rg] * iv);
  }
  if (hi == 0) {
    size_t grow = (size_t)kq * 16384 + batch * 4096 + q0 + ln;
    Ml[grow * 2] = m_;
    Ml[grow * 2 + 1] = l_;
  }
#undef STAGE
#undef SOFTMAX
}

// ---- Kernel D: split-K merge (m stored in log2 domain -> exp2 weights) ----
__global__ __launch_bounds__(256) void merge_kernel(
    const f16* __restrict__ Opart, const float* __restrict__ Ml,
    float* __restrict__ out) {
  int gid = blockIdx.x * 256 + threadIdx.x;
  int row = gid >> 5, d0 = (gid & 31) * 8;
  float m[4], l[4];
  #pragma unroll
  for (int p = 0; p < 4; ++p) {
    m[p] = Ml[((size_t)p * 16384 + row) * 2];
    l[p] = Ml[((size_t)p * 16384 + row) * 2 + 1];
  }
  float M = fmaxf(fmaxf(m[0], m[1]), fmaxf(m[2], m[3]));
  float wl[4], L = 0.f;
  #pragma unroll
  for (int p = 0; p < 4; ++p) { wl[p] = exp2f(m[p] - M) * l[p]; L += wl[p]; }
  float o[8] = {0.f, 0.f, 0.f, 0.f, 0.f, 0.f, 0.f, 0.f};
  #pragma unroll
  for (int p = 0; p < 4; ++p) {
    f16x8 v = *(const f16x8*)(Opart + ((size_t)p * 16384 + row) * 256 + d0);
    #pragma unroll
    for (int j = 0; j < 8; ++j) o[j] += wl[p] * (float)v[j];
  }
  float invL = 1.0f / L;
  float4 o0 = {o[0] * invL, o[1] * invL, o[2] * invL, o[3] * invL};
  float4 o1 = {o[4] * invL, o[5] * invL, o[6] * invL, o[7] * invL};
  *(float4*)(out + (size_t)row * 256 + d0) = o0;
  *(float4*)(out + (size_t)row * 256 + d0 + 4) = o1;
}

extern "C" void kernel_launch(void* const* d_in, const int* in_sizes, int n_in,
                              void* d_out, int out_size, void* d_ws, size_t ws_size,
                              hipStream_t stream) {
  const float* x  = (const float*)d_in[0];
  const float* Wq = (const float*)d_in[1];
  const float* bq = (const float*)d_in[2];
  const float* Wk = (const float*)d_in[3];
  const float* bk = (const float*)d_in[4];
  const float* Wv = (const float*)d_in[5];
  const float* bv = (const float*)d_in[6];
  float* out = (float*)d_out;

  u16* Wh = (u16*)d_ws;
  u16* Wl = Wh + 3 * 65536;
  f16* Qf = (f16*)(Wl + 3 * 65536);
  f16* Kf = Qf + (size_t)16384 * 256;
  f16* Vt = Kf + (size_t)16384 * 256;
  f16* Opart = Vt + (size_t)4 * 256 * 4096;
  float* Ml = (float*)(Opart + (size_t)4 * 16384 * 256);

  wt_kernel<<<48, 256, 0, stream>>>(Wq, Wk, Wv, Wh, Wl);
  proj_kernel<<<dim3(128, 3), 256, 0, stream>>>(x, bq, bk, bv, Wh, Wl, Qf, Kf, Vt);
  attn_kernel<<<256, 512, 0, stream>>>(Qf, Kf, Vt, Opart, Ml);
  merge_kernel<<<2048, 256, 0, stream>>>(Opart, Ml, out);
}